// Round 16
// baseline (196.298 us; speedup 1.0000x reference)
//
#include <hip/hip_runtime.h>

#define FDIM 128
#define UDIM 128
#define BROWS 32             // rows per bucket
#define CAP   1408           // max edges/bucket (mean 1056, +10.7 sigma)
#define TILE  4096           // edges per bin tile
#define EPT   16             // edges per thread in bin tile

typedef __attribute__((ext_vector_type(8))) short short8;   // 8 bf16
typedef __attribute__((ext_vector_type(4))) float floatx4;  // mfma acc

__device__ inline unsigned int round_bf16_bits(float a) {
  unsigned int ua = __float_as_uint(a);
  ua += 0x7fffu + ((ua >> 16) & 1u);
  return ua & 0xffff0000u;
}
__device__ inline unsigned int pack_bf16(float a, float b) {
  unsigned int ua = __float_as_uint(a);
  unsigned int ub = __float_as_uint(b);
  ua += 0x7fffu + ((ua >> 16) & 1u);
  ub += 0x7fffu + ((ub >> 16) & 1u);
  return (ua >> 16) | (ub & 0xffff0000u);
}

// ---------------------------------------------------------------------------
// prep: zero diag+cursor (contiguous) and build kfrag (MFMA B-frags of K)
// ---------------------------------------------------------------------------
__global__ __launch_bounds__(256) void prep(
    const float* __restrict__ K, uint4* __restrict__ kfrag,
    int* __restrict__ zbase, int zcount) {
  int gid = blockIdx.x * 256 + threadIdx.x;
  if (gid < 2048) {
    int lane = gid & 63, bb = gid >> 6;
    int n = (bb >> 2) * 16 + (lane & 15);
    int k0 = (bb & 3) * 32 + (lane >> 4) * 8;
    unsigned int pq[4];
    #pragma unroll
    for (int j = 0; j < 4; ++j) {
      float a = K[(size_t)(k0 + 2 * j) * UDIM + n];
      float b = K[(size_t)(k0 + 2 * j + 1) * UDIM + n];
      pq[j] = pack_bf16(a, b);
    }
    kfrag[gid] = make_uint4(pq[0], pq[1], pq[2], pq[3]);
  }
  if (gid < zcount) zbase[gid] = 0;
}

// ---------------------------------------------------------------------------
// bin_dev: bucket = src >> 5 (1563 buckets). Single 8B store per edge:
// meta[pos] = {w_bf16|dst, src&31}. Also accumulates diag (self-loops).
// ---------------------------------------------------------------------------
__device__ void bin_dev(int blk, const int* __restrict__ src,
                        const int* __restrict__ dst, const float* __restrict__ w,
                        int* __restrict__ cursor, uint2* __restrict__ meta,
                        float* __restrict__ diag, int E, int NB, char* smem) {
  int* scnt  = (int*)smem;          // NB ints
  int* sbase = scnt + NB;
  int* scur  = sbase + NB;
  int t = threadIdx.x;
  for (int b = t; b < NB; b += 256) { scnt[b] = 0; scur[b] = 0; }
  __syncthreads();

  uint2 pay[EPT];
  int e0 = blk * TILE;
  #pragma unroll
  for (int j = 0; j < EPT; ++j) {
    int e = e0 + j * 256 + t;
    if (e < E) {
      int s = src[e];
      int d = dst[e];
      float wv = w[e];
      if (s == d) atomicAdd(&diag[s], wv);
      pay[j].x = round_bf16_bits(wv) | (unsigned int)d;
      pay[j].y = (unsigned int)s;
      atomicAdd(&scnt[s >> 5], 1);
    } else {
      pay[j].y = 0xffffffffu;
    }
  }
  __syncthreads();

  for (int b = t; b < NB; b += 256) {
    int c = scnt[b];
    if (c) sbase[b] = b * CAP + atomicAdd(&cursor[b], c);
  }
  __syncthreads();

  #pragma unroll
  for (int j = 0; j < EPT; ++j) {
    if (pay[j].y != 0xffffffffu) {
      int b = (int)(pay[j].y >> 5);
      int r = atomicAdd(&scur[b], 1);
      int pos = sbase[b] + r;
      if (pos < (b + 1) * CAP)
        meta[pos] = make_uint2(pay[j].x, pay[j].y & 31u);
    }
  }
}

// ---------------------------------------------------------------------------
// gemm_dev: one 64-row MFMA tile of Y = X @ K (bf16 16x16x32), kfrag B-frags
// ---------------------------------------------------------------------------
__device__ void gemm_dev(int g, const float* __restrict__ x,
                         const uint4* __restrict__ kfrag,
                         unsigned short* __restrict__ Ybf, int N, char* smem) {
  unsigned short (*sX)[136] = (unsigned short (*)[136])smem;
  int t = threadIdx.x;
  int r0 = g * 64;

  #pragma unroll
  for (int i = 0; i < 8; ++i) {
    int li = i * 256 + t;
    int row = li >> 5;
    int col4 = (li & 31) * 4;
    int gr = r0 + row; if (gr > N - 1) gr = N - 1;
    float4 v = *(const float4*)(x + (size_t)gr * FDIM + col4);
    *(uint2*)(&sX[row][col4]) = make_uint2(pack_bf16(v.x, v.y), pack_bf16(v.z, v.w));
  }
  __syncthreads();

  int wave = t >> 6, lane = t & 63;
  int m = lane & 15, q = lane >> 4;

  short8 bf[2][4];
  #pragma unroll
  for (int c = 0; c < 2; ++c)
    #pragma unroll
    for (int ks = 0; ks < 4; ++ks)
      bf[c][ks] = *(const short8*)&kfrag[(size_t)((2 * wave + c) * 4 + ks) * 64 + lane];

  floatx4 acc[4][2];
  #pragma unroll
  for (int rt = 0; rt < 4; ++rt)
    #pragma unroll
    for (int c = 0; c < 2; ++c)
      acc[rt][c] = (floatx4){0.f, 0.f, 0.f, 0.f};

  #pragma unroll
  for (int ks = 0; ks < 4; ++ks) {
    #pragma unroll
    for (int rt = 0; rt < 4; ++rt) {
      short8 af = *(const short8*)&sX[rt * 16 + m][ks * 32 + q * 8];
      acc[rt][0] = __builtin_amdgcn_mfma_f32_16x16x32_bf16(af, bf[0][ks], acc[rt][0], 0, 0, 0);
      acc[rt][1] = __builtin_amdgcn_mfma_f32_16x16x32_bf16(af, bf[1][ks], acc[rt][1], 0, 0, 0);
    }
  }

  #pragma unroll
  for (int rt = 0; rt < 4; ++rt) {
    #pragma unroll
    for (int c = 0; c < 2; ++c) {
      int col = (2 * wave + c) * 16 + m;
      #pragma unroll
      for (int reg = 0; reg < 4; ++reg) {
        int r = r0 + rt * 16 + q * 4 + reg;
        if (r < N)
          Ybf[(size_t)r * UDIM + col] =
              (unsigned short)(round_bf16_bits(acc[rt][c][reg]) >> 16);
      }
    }
  }
}

// ---------------------------------------------------------------------------
// bin_gemm: heterogeneous dispatch; blocks [0,nbin) bin, rest do GEMM tiles.
// ---------------------------------------------------------------------------
__global__ __launch_bounds__(256) void bin_gemm(
    const int* __restrict__ src, const int* __restrict__ dst,
    const float* __restrict__ w, int* __restrict__ cursor,
    uint2* __restrict__ meta, float* __restrict__ diag,
    const float* __restrict__ x, const uint4* __restrict__ kfrag,
    unsigned short* __restrict__ Ybf, int N, int E, int NB, int nbin) {
  __shared__ alignas(16) char smem[18816];   // max(bin 3*NB*4=18756, gemm 17408)
  if (blockIdx.x < (unsigned)nbin)
    bin_dev(blockIdx.x, src, dst, w, cursor, meta, diag, E, NB, smem);
  else
    gemm_dev(blockIdx.x - nbin, x, kfrag, Ybf, N, smem);
}

// ---------------------------------------------------------------------------
// sort_gather: one block per 32-row bucket. LDS counting sort, then gather
// with PAIRED-EDGE uint4 loads: half-wave = 2 edge-slots x 16 col-groups,
// each lane loads 16B (8 bf16 cols) -> 2x bytes in flight per instruction.
// shfl_xor(16) combines the two edge-slot partials per row. Fused epilogue.
// ---------------------------------------------------------------------------
__global__ __launch_bounds__(256, 8) void sort_gather(
    const unsigned short* __restrict__ Ybf, const uint2* __restrict__ meta,
    const int* __restrict__ cursor, const float* __restrict__ diag,
    const float* __restrict__ x, const float* __restrict__ K,
    const float* __restrict__ bias, float* __restrict__ out, int N) {
  __shared__ unsigned int sdstw[CAP];      // 5632 B
  __shared__ unsigned int sorted[CAP];     // 5632 B
  __shared__ unsigned char skey[CAP];      // 1408 B
  __shared__ int kcnt[BROWS];
  __shared__ int rstart[BROWS + 1];
  int b = blockIdx.x;
  int t = threadIdx.x;
  int cntE = cursor[b]; if (cntE > CAP) cntE = CAP;
  const uint2* mb = meta + (size_t)b * CAP;

  if (t < BROWS) kcnt[t] = 0;
  __syncthreads();

  for (int e = t; e < cntE; e += 256) {
    uint2 m = mb[e];
    sdstw[e] = m.x;
    skey[e] = (unsigned char)m.y;
    atomicAdd(&kcnt[m.y & 31u], 1);
  }
  __syncthreads();

  if (t < BROWS) {
    int v = kcnt[t];
    int incl = v;
    #pragma unroll
    for (int off = 1; off < BROWS; off <<= 1) {
      int u = __shfl_up(incl, off, 64);
      if (t >= off) incl += u;
    }
    rstart[t + 1] = incl;
    kcnt[t] = incl - v;
    if (t == 0) rstart[0] = 0;
  }
  __syncthreads();

  for (int e = t; e < cntE; e += 256) {
    int k = skey[e];
    int pos = atomicAdd(&kcnt[k], 1);
    sorted[pos] = sdstw[e];
  }
  __syncthreads();

  // gather: 8 half-wave slots, 4 passes over 32 rows
  int lane = t & 63, sub = lane & 31;
  int slot16 = (sub >> 4) & 1;      // edge of the pair
  int cg = sub & 15;                // col-group: cols [cg*8, cg*8+8)
  int hslot = (t >> 6) * 2 + (lane >> 5);
  for (int p = 0; p < 4; ++p) {
    int rl = p * 8 + hslot;
    int g = b * BROWS + rl;
    int base = rstart[rl], end = rstart[rl + 1];

    float4 a0 = {0.f, 0.f, 0.f, 0.f};
    float4 a1 = {0.f, 0.f, 0.f, 0.f};
    if (end > base) {
      for (int i = base; i < end; i += 12) {
        unsigned int mi[6];
        #pragma unroll
        for (int j = 0; j < 6; ++j) {
          int raw = i + 2 * j + slot16;
          int idx = raw < end ? raw : end - 1;
          unsigned int v = sorted[idx];
          mi[j] = raw < end ? v : (v & 0xffffu);   // OOB -> weight 0
        }
        uint4 pk[6];
        #pragma unroll
        for (int j = 0; j < 6; ++j)
          pk[j] = *(const uint4*)(Ybf + (size_t)(mi[j] & 0xffffu) * UDIM + cg * 8);
        #pragma unroll
        for (int j = 0; j < 6; ++j) {
          float wj = __uint_as_float(mi[j] & 0xffff0000u);
          a0.x += wj * __uint_as_float(pk[j].x << 16);
          a0.y += wj * __uint_as_float(pk[j].x & 0xffff0000u);
          a0.z += wj * __uint_as_float(pk[j].y << 16);
          a0.w += wj * __uint_as_float(pk[j].y & 0xffff0000u);
          a1.x += wj * __uint_as_float(pk[j].z << 16);
          a1.y += wj * __uint_as_float(pk[j].z & 0xffff0000u);
          a1.z += wj * __uint_as_float(pk[j].w << 16);
          a1.w += wj * __uint_as_float(pk[j].w & 0xffff0000u);
        }
      }
    }
    // combine the two edge-slot partials (partner = lane ^ 16 within 32-group)
    a0.x += __shfl_xor(a0.x, 16, 32);
    a0.y += __shfl_xor(a0.y, 16, 32);
    a0.z += __shfl_xor(a0.z, 16, 32);
    a0.w += __shfl_xor(a0.w, 16, 32);
    a1.x += __shfl_xor(a1.x, 16, 32);
    a1.y += __shfl_xor(a1.y, 16, 32);
    a1.z += __shfl_xor(a1.z, 16, 32);
    a1.w += __shfl_xor(a1.w, 16, 32);

    if (g < N) {
      int c0 = cg * 8;
      float dg = diag[g];
      const int lf[4] = {0, 5, 17, 42};
      #pragma unroll
      for (int tt = 0; tt < 4; ++tt) {
        float c = dg * x[(size_t)g * FDIM + lf[tt]];
        float4 ka = *(const float4*)(K + (size_t)lf[tt] * UDIM + c0);
        float4 kb = *(const float4*)(K + (size_t)lf[tt] * UDIM + c0 + 4);
        a0.x -= c * ka.x; a0.y -= c * ka.y; a0.z -= c * ka.z; a0.w -= c * ka.w;
        a1.x -= c * kb.x; a1.y -= c * kb.y; a1.z -= c * kb.z; a1.w -= c * kb.w;
      }
      float4 ba = *(const float4*)(bias + c0);
      float4 bb = *(const float4*)(bias + c0 + 4);
      a0.x = fmaxf(a0.x + ba.x, 0.f); a0.y = fmaxf(a0.y + ba.y, 0.f);
      a0.z = fmaxf(a0.z + ba.z, 0.f); a0.w = fmaxf(a0.w + ba.w, 0.f);
      a1.x = fmaxf(a1.x + bb.x, 0.f); a1.y = fmaxf(a1.y + bb.y, 0.f);
      a1.z = fmaxf(a1.z + bb.z, 0.f); a1.w = fmaxf(a1.w + bb.w, 0.f);
      // both halves hold identical data; each stores its float4
      float4 sv = slot16 ? a1 : a0;
      *(float4*)(out + (size_t)g * UDIM + c0 + slot16 * 4) = sv;
    }
  }
}

extern "C" void kernel_launch(void* const* d_in, const int* in_sizes, int n_in,
                              void* d_out, int out_size, void* d_ws, size_t ws_size,
                              hipStream_t stream) {
  const float* x    = (const float*)d_in[0];
  const int*   esrc = (const int*)d_in[1];
  const int*   edst = (const int*)d_in[2];
  const float* ew   = (const float*)d_in[3];
  const float* K    = (const float*)d_in[4];
  const float* bias = (const float*)d_in[5];
  float* out = (float*)d_out;

  const int N = in_sizes[0] / FDIM;
  const int E = in_sizes[1];
  const int NB = (N + BROWS - 1) / BROWS;   // 1563 buckets

  // workspace layout (~31 MB); diag+cursor contiguous (zeroed by prep)
  char* p = (char*)d_ws;
  unsigned short* Ybf = (unsigned short*)p; p += (size_t)N * UDIM * 2;
  float* diag  = (float*)p;         p += (size_t)N * 4;
  int*   cursor = (int*)p;          p += (size_t)NB * 4;
  uint4* kfrag = (uint4*)p;         p += (size_t)32 * 64 * 16;
  uint2* meta = (uint2*)p;          p += (size_t)NB * CAP * 8;

  const int nbin = (E + TILE - 1) / TILE;   // 403
  const int ngemm = (N + 63) / 64;          // 782

  prep<<<(N + NB + 255) / 256, 256, 0, stream>>>(K, kfrag, (int*)diag, N + NB);
  bin_gemm<<<nbin + ngemm, 256, 0, stream>>>(
      esrc, edst, ew, cursor, meta, diag, x, kfrag, Ybf, N, E, NB, nbin);
  sort_gather<<<NB, 256, 0, stream>>>(Ybf, meta, cursor, diag, x, K, bias, out, N);
}

// Round 17
// 186.134 us; speedup vs baseline: 1.0546x; 1.0546x over previous
//
#include <hip/hip_runtime.h>

#define FDIM 128
#define UDIM 128
#define BROWS 32             // rows per bucket
#define CAP   1408           // max edges/bucket (mean 1056, +10.7 sigma)
#define CAP16 768            // max edges per 16-row half-bucket (mean 528)
#define TILE  4096           // edges per bin tile
#define EPT   16             // edges per thread in bin tile

typedef __attribute__((ext_vector_type(8))) short short8;   // 8 bf16
typedef __attribute__((ext_vector_type(4))) float floatx4;  // mfma acc

__device__ inline unsigned int round_bf16_bits(float a) {
  unsigned int ua = __float_as_uint(a);
  ua += 0x7fffu + ((ua >> 16) & 1u);
  return ua & 0xffff0000u;
}
__device__ inline unsigned int pack_bf16(float a, float b) {
  unsigned int ua = __float_as_uint(a);
  unsigned int ub = __float_as_uint(b);
  ua += 0x7fffu + ((ua >> 16) & 1u);
  ub += 0x7fffu + ((ub >> 16) & 1u);
  return (ua >> 16) | (ub & 0xffff0000u);
}

// ---------------------------------------------------------------------------
// prep: zero diag+cursor (contiguous) and build kfrag (MFMA B-frags of K)
// ---------------------------------------------------------------------------
__global__ __launch_bounds__(256) void prep(
    const float* __restrict__ K, uint4* __restrict__ kfrag,
    int* __restrict__ zbase, int zcount) {
  int gid = blockIdx.x * 256 + threadIdx.x;
  if (gid < 2048) {
    int lane = gid & 63, bb = gid >> 6;
    int n = (bb >> 2) * 16 + (lane & 15);
    int k0 = (bb & 3) * 32 + (lane >> 4) * 8;
    unsigned int pq[4];
    #pragma unroll
    for (int j = 0; j < 4; ++j) {
      float a = K[(size_t)(k0 + 2 * j) * UDIM + n];
      float b = K[(size_t)(k0 + 2 * j + 1) * UDIM + n];
      pq[j] = pack_bf16(a, b);
    }
    kfrag[gid] = make_uint4(pq[0], pq[1], pq[2], pq[3]);
  }
  if (gid < zcount) zbase[gid] = 0;
}

// ---------------------------------------------------------------------------
// bin_dev: bucket = src >> 5 (1563 buckets). Single 8B store per edge:
// meta[pos] = {w_bf16|dst, src&31}. Also accumulates diag (self-loops).
// ---------------------------------------------------------------------------
__device__ void bin_dev(int blk, const int* __restrict__ src,
                        const int* __restrict__ dst, const float* __restrict__ w,
                        int* __restrict__ cursor, uint2* __restrict__ meta,
                        float* __restrict__ diag, int E, int NB, char* smem) {
  int* scnt  = (int*)smem;          // NB ints
  int* sbase = scnt + NB;
  int* scur  = sbase + NB;
  int t = threadIdx.x;
  for (int b = t; b < NB; b += 256) { scnt[b] = 0; scur[b] = 0; }
  __syncthreads();

  uint2 pay[EPT];
  int e0 = blk * TILE;
  #pragma unroll
  for (int j = 0; j < EPT; ++j) {
    int e = e0 + j * 256 + t;
    if (e < E) {
      int s = src[e];
      int d = dst[e];
      float wv = w[e];
      if (s == d) atomicAdd(&diag[s], wv);
      pay[j].x = round_bf16_bits(wv) | (unsigned int)d;
      pay[j].y = (unsigned int)s;
      atomicAdd(&scnt[s >> 5], 1);
    } else {
      pay[j].y = 0xffffffffu;
    }
  }
  __syncthreads();

  for (int b = t; b < NB; b += 256) {
    int c = scnt[b];
    if (c) sbase[b] = b * CAP + atomicAdd(&cursor[b], c);
  }
  __syncthreads();

  #pragma unroll
  for (int j = 0; j < EPT; ++j) {
    if (pay[j].y != 0xffffffffu) {
      int b = (int)(pay[j].y >> 5);
      int r = atomicAdd(&scur[b], 1);
      int pos = sbase[b] + r;
      if (pos < (b + 1) * CAP)
        meta[pos] = make_uint2(pay[j].x, pay[j].y & 31u);
    }
  }
}

// ---------------------------------------------------------------------------
// gemm_dev: one 64-row MFMA tile of Y = X @ K (bf16 16x16x32), kfrag B-frags
// ---------------------------------------------------------------------------
__device__ void gemm_dev(int g, const float* __restrict__ x,
                         const uint4* __restrict__ kfrag,
                         unsigned short* __restrict__ Ybf, int N, char* smem) {
  unsigned short (*sX)[136] = (unsigned short (*)[136])smem;
  int t = threadIdx.x;
  int r0 = g * 64;

  #pragma unroll
  for (int i = 0; i < 8; ++i) {
    int li = i * 256 + t;
    int row = li >> 5;
    int col4 = (li & 31) * 4;
    int gr = r0 + row; if (gr > N - 1) gr = N - 1;
    float4 v = *(const float4*)(x + (size_t)gr * FDIM + col4);
    *(uint2*)(&sX[row][col4]) = make_uint2(pack_bf16(v.x, v.y), pack_bf16(v.z, v.w));
  }
  __syncthreads();

  int wave = t >> 6, lane = t & 63;
  int m = lane & 15, q = lane >> 4;

  short8 bf[2][4];
  #pragma unroll
  for (int c = 0; c < 2; ++c)
    #pragma unroll
    for (int ks = 0; ks < 4; ++ks)
      bf[c][ks] = *(const short8*)&kfrag[(size_t)((2 * wave + c) * 4 + ks) * 64 + lane];

  floatx4 acc[4][2];
  #pragma unroll
  for (int rt = 0; rt < 4; ++rt)
    #pragma unroll
    for (int c = 0; c < 2; ++c)
      acc[rt][c] = (floatx4){0.f, 0.f, 0.f, 0.f};

  #pragma unroll
  for (int ks = 0; ks < 4; ++ks) {
    #pragma unroll
    for (int rt = 0; rt < 4; ++rt) {
      short8 af = *(const short8*)&sX[rt * 16 + m][ks * 32 + q * 8];
      acc[rt][0] = __builtin_amdgcn_mfma_f32_16x16x32_bf16(af, bf[0][ks], acc[rt][0], 0, 0, 0);
      acc[rt][1] = __builtin_amdgcn_mfma_f32_16x16x32_bf16(af, bf[1][ks], acc[rt][1], 0, 0, 0);
    }
  }

  #pragma unroll
  for (int rt = 0; rt < 4; ++rt) {
    #pragma unroll
    for (int c = 0; c < 2; ++c) {
      int col = (2 * wave + c) * 16 + m;
      #pragma unroll
      for (int reg = 0; reg < 4; ++reg) {
        int r = r0 + rt * 16 + q * 4 + reg;
        if (r < N)
          Ybf[(size_t)r * UDIM + col] =
              (unsigned short)(round_bf16_bits(acc[rt][c][reg]) >> 16);
      }
    }
  }
}

// ---------------------------------------------------------------------------
// bin_gemm: heterogeneous dispatch; blocks [0,nbin) bin, rest do GEMM tiles.
// ---------------------------------------------------------------------------
__global__ __launch_bounds__(256) void bin_gemm(
    const int* __restrict__ src, const int* __restrict__ dst,
    const float* __restrict__ w, int* __restrict__ cursor,
    uint2* __restrict__ meta, float* __restrict__ diag,
    const float* __restrict__ x, const uint4* __restrict__ kfrag,
    unsigned short* __restrict__ Ybf, int N, int E, int NB, int nbin) {
  __shared__ alignas(16) char smem[18816];   // max(bin 3*NB*4=18756, gemm 17408)
  if (blockIdx.x < (unsigned)nbin)
    bin_dev(blockIdx.x, src, dst, w, cursor, meta, diag, E, NB, smem);
  else
    gemm_dev(blockIdx.x - nbin, x, kfrag, Ybf, N, smem);
}

// ---------------------------------------------------------------------------
// sort_gather: one block per 16-row HALF-bucket (2 blocks/bucket, 3126 total,
// 3.3 KB LDS -> residency capped by waves not LDS; better balance/tail).
// Two passes over the bucket's meta: count own rows (4B reads), scatter own
// edges into LDS row-grouped array. Then r12's 8-deep uint2 gather + epilogue.
// ---------------------------------------------------------------------------
__global__ __launch_bounds__(256) void sort_gather(
    const unsigned short* __restrict__ Ybf, const uint2* __restrict__ meta,
    const int* __restrict__ cursor, const float* __restrict__ diag,
    const float* __restrict__ x, const float* __restrict__ K,
    const float* __restrict__ bias, float* __restrict__ out, int N) {
  __shared__ unsigned int sorted[CAP16];   // 3072 B
  __shared__ int kcnt[16];
  __shared__ int rstart[17];
  int blk = blockIdx.x;
  int bkt = blk >> 1;
  int half = blk & 1;
  int t = threadIdx.x;
  int cntE = cursor[bkt]; if (cntE > CAP) cntE = CAP;
  const uint2* mb = meta + (size_t)bkt * CAP;

  if (t < 16) kcnt[t] = 0;
  __syncthreads();

  // pass 1: count this half's rows (read only the 4B row field)
  for (int e = t; e < cntE; e += 256) {
    unsigned int row = mb[e].y;
    if ((int)(row >> 4) == half) atomicAdd(&kcnt[row & 15u], 1);
  }
  __syncthreads();

  // lanes 0..15 of wave 0: inclusive scan -> rstart, exclusive cursors
  if (t < 16) {
    int v = kcnt[t];
    int incl = v;
    #pragma unroll
    for (int off = 1; off < 16; off <<= 1) {
      int u = __shfl_up(incl, off, 64);
      if (t >= off) incl += u;
    }
    rstart[t + 1] = incl > CAP16 ? CAP16 : incl;
    kcnt[t] = incl - v;
    if (t == 0) rstart[0] = 0;
  }
  __syncthreads();

  // pass 2: scatter own edges into row-grouped LDS array
  for (int e = t; e < cntE; e += 256) {
    uint2 m = mb[e];
    if ((int)(m.y >> 4) == half) {
      int pos = atomicAdd(&kcnt[m.y & 15u], 1);
      if (pos < CAP16) sorted[pos] = m.x;
    }
  }
  __syncthreads();

  // gather: 8 half-wave slots, 2 passes over 16 rows (r12 inner loop)
  int lane = t & 63, sub = lane & 31;
  int hslot = (t >> 6) * 2 + (lane >> 5);
  for (int p = 0; p < 2; ++p) {
    int rl = p * 8 + hslot;
    int g = bkt * BROWS + half * 16 + rl;
    int base = rstart[rl], end = rstart[rl + 1];

    float4 acc = {0.f, 0.f, 0.f, 0.f};
    int i = base;
    for (; i + 8 <= end; i += 8) {
      unsigned int mi[8];
      #pragma unroll
      for (int j = 0; j < 8; ++j) mi[j] = sorted[i + j];   // LDS broadcast
      uint2 pk[8];
      #pragma unroll
      for (int j = 0; j < 8; ++j)
        pk[j] = *(const uint2*)(Ybf + (size_t)(mi[j] & 0xffffu) * UDIM + sub * 4);
      #pragma unroll
      for (int j = 0; j < 8; ++j) {
        float wj = __uint_as_float(mi[j] & 0xffff0000u);
        acc.x += wj * __uint_as_float(pk[j].x << 16);
        acc.y += wj * __uint_as_float(pk[j].x & 0xffff0000u);
        acc.z += wj * __uint_as_float(pk[j].y << 16);
        acc.w += wj * __uint_as_float(pk[j].y & 0xffff0000u);
      }
    }
    for (; i < end; ++i) {
      unsigned int mi = sorted[i];
      float wj = __uint_as_float(mi & 0xffff0000u);
      uint2 pk = *(const uint2*)(Ybf + (size_t)(mi & 0xffffu) * UDIM + sub * 4);
      acc.x += wj * __uint_as_float(pk.x << 16);
      acc.y += wj * __uint_as_float(pk.x & 0xffff0000u);
      acc.z += wj * __uint_as_float(pk.y << 16);
      acc.w += wj * __uint_as_float(pk.y & 0xffff0000u);
    }

    if (g < N) {
      float dg = diag[g];
      const int lf[4] = {0, 5, 17, 42};
      #pragma unroll
      for (int tt = 0; tt < 4; ++tt) {
        float c = dg * x[(size_t)g * FDIM + lf[tt]];
        float4 k4 = *(const float4*)(K + (size_t)lf[tt] * UDIM + sub * 4);
        acc.x -= c * k4.x; acc.y -= c * k4.y;
        acc.z -= c * k4.z; acc.w -= c * k4.w;
      }
      float4 b4 = *(const float4*)(bias + sub * 4);
      acc.x = fmaxf(acc.x + b4.x, 0.f);
      acc.y = fmaxf(acc.y + b4.y, 0.f);
      acc.z = fmaxf(acc.z + b4.z, 0.f);
      acc.w = fmaxf(acc.w + b4.w, 0.f);
      *(float4*)(out + (size_t)g * UDIM + sub * 4) = acc;
    }
  }
}

extern "C" void kernel_launch(void* const* d_in, const int* in_sizes, int n_in,
                              void* d_out, int out_size, void* d_ws, size_t ws_size,
                              hipStream_t stream) {
  const float* x    = (const float*)d_in[0];
  const int*   esrc = (const int*)d_in[1];
  const int*   edst = (const int*)d_in[2];
  const float* ew   = (const float*)d_in[3];
  const float* K    = (const float*)d_in[4];
  const float* bias = (const float*)d_in[5];
  float* out = (float*)d_out;

  const int N = in_sizes[0] / FDIM;
  const int E = in_sizes[1];
  const int NB = (N + BROWS - 1) / BROWS;   // 1563 buckets

  // workspace layout (~31 MB); diag+cursor contiguous (zeroed by prep)
  char* p = (char*)d_ws;
  unsigned short* Ybf = (unsigned short*)p; p += (size_t)N * UDIM * 2;
  float* diag  = (float*)p;         p += (size_t)N * 4;
  int*   cursor = (int*)p;          p += (size_t)NB * 4;
  uint4* kfrag = (uint4*)p;         p += (size_t)32 * 64 * 16;
  uint2* meta = (uint2*)p;          p += (size_t)NB * CAP * 8;

  const int nbin = (E + TILE - 1) / TILE;   // 403
  const int ngemm = (N + 63) / 64;          // 782

  prep<<<(N + NB + 255) / 256, 256, 0, stream>>>(K, kfrag, (int*)diag, N + NB);
  bin_gemm<<<nbin + ngemm, 256, 0, stream>>>(
      esrc, edst, ew, cursor, meta, diag, x, kfrag, Ybf, N, E, NB, nbin);
  sort_gather<<<NB * 2, 256, 0, stream>>>(Ybf, meta, cursor, diag, x, K, bias, out, N);
}